// Round 3
// baseline (463.109 us; speedup 1.0000x reference)
//
#include <hip/hip_runtime.h>
#include <hip/hip_bf16.h>
#include <math.h>

// SGConv: x = emb[x_indices]; 3 hops of D^-1/2 (A+I) D^-1/2; out = x3 @ W^T + b.
// z-space: z = dinv*x; hop: z' = dinv^2*(z[c] + sum_{r->c} z[r]); last hop dinv^1.
// LEDGER (verified r0-18): emb/w/b fp32, out fp32, ei contiguous (2,E),
// index widths runtime-classified, bf16 z validated (absmax 4.9e-4).
// r17: un-fuse z0 from p4 (parallelism-starved). r18: W-precompute in p2a's
// extra block + fused hop3+linear (zA->out), -10us.
// r19: SOURCE-SLICED HOPS. Theory: hops are L2-residency bound (z = 12.8MB
// vs 4MB per-XCD L2 -> ~31% hit; ~140MB/hop from L3 at high latency). Sort
// each node's edge list by source (insertion-sort tail in p4), then hop
// sweeps sources in npass~4 slices of ~3.2MB so resident waves gather from
// an L2-resident slice. Self-loop folded into its slice's pass; zout stores
// + rowidx reads nontemporal to protect L2. Sorted order makes the unroll-4
// batch check a single compare (r3 = max).
// r19b (this round): fix compile — __builtin_nontemporal_store needs a
// native ext_vector type, not HIP's uint4 class; store via uint32x4 cast.
// Keep: 4B packed staging, folded p2b, contiguous unroll-4 hop core.

#define FLAG_MX 0
#define FLAG_ME 1
#define SH 9        // 512 cols per bucket
#define WC 512      // cols per bucket
#define CH 4096     // edges per P1/P3 block
#define RMASK 0x7FFFFFu

using short8 = __attribute__((ext_vector_type(8))) short;
using f32x4 = __attribute__((ext_vector_type(4))) float;
using uint32x4 = __attribute__((ext_vector_type(4))) unsigned;

__device__ inline int idx_at(const void* p, long long i, int mode) {
    switch (mode) {
        case 1: return (int)((const long long*)p)[i];
        case 2: return (int)((const float*)p)[i];
        case 3: return (int)((const double*)p)[i];
        default: return ((const int*)p)[i];
    }
}

// bf16 helpers (RNE pack, shift unpack)
__device__ inline unsigned short f2bf(float f) {
    union { float f; unsigned u; } v; v.f = f;
    unsigned r = v.u + 0x7FFFu + ((v.u >> 16) & 1u);
    return (unsigned short)(r >> 16);
}
__device__ inline float bflo(unsigned d) { union { unsigned u; float f; } v; v.u = d << 16; return v.f; }
__device__ inline float bfhi(unsigned d) { union { unsigned u; float f; } v; v.u = d & 0xFFFF0000u; return v.f; }
__device__ inline unsigned pk(float a, float b) {
    return (unsigned)f2bf(a) | ((unsigned)f2bf(b) << 16);
}

__device__ int detect_me_block(const void* ei, int n, int* sbuf) {
    int t = threadIdx.x;
    int oke = 15;
    const int* w = (const int*)ei;
    const long long* L = (const long long*)ei;
    const float* f = (const float*)ei;
    const double* d = (const double*)ei;
    for (int k = t; k < 2048; k += 256) {
        if (!((unsigned)w[k] < (unsigned)n)) oke &= ~1;
        long long lv = L[k];
        if (!(lv >= 0 && lv < (long long)n)) oke &= ~2;
        float fv = f[k];
        if (!(fv >= 0.f && fv < (float)n && fv == truncf(fv))) oke &= ~4;
        double dv = d[k];
        if (!(dv >= 0.0 && dv < (double)n && dv == trunc(dv))) oke &= ~8;
    }
    sbuf[t] = oke;
    __syncthreads();
    for (int st = 128; st; st >>= 1) {
        if (t < st) sbuf[t] &= sbuf[t + st];
        __syncthreads();
    }
    int r = sbuf[0];
    __syncthreads();
    return (r & 2) ? 1 : (r & 8) ? 3 : (r & 4) ? 2 : 0;
}

__device__ int detect_mx_block(const void* xidx, int* sbuf) {
    int t = threadIdx.x;
    int okx = 15;
    const int* w = (const int*)xidx;
    const long long* L = (const long long*)xidx;
    const float* f = (const float*)xidx;
    const double* d = (const double*)xidx;
    for (int k = t; k < 2048; k += 256) {
        if (w[k] != k) okx &= ~1;
        if (L[k] != (long long)k) okx &= ~2;
        if (!(f[k] == (float)k)) okx &= ~4;
        if (!(d[k] == (double)k)) okx &= ~8;
    }
    sbuf[t] = okx;
    __syncthreads();
    for (int st = 128; st; st >>= 1) {
        if (t < st) sbuf[t] &= sbuf[t + st];
        __syncthreads();
    }
    int r = sbuf[0];
    __syncthreads();
    return (r & 2) ? 1 : (r & 8) ? 3 : (r & 4) ? 2 : 0;
}

// P1: inline classify (block 0 publishes flags) + per-block bucket histogram
// -> bhist[b*NBLK + blk] (bucket-major).
__global__ void __launch_bounds__(256) k_p1(
        const void* __restrict__ ei, const void* __restrict__ xidx,
        long long E, int n, int NBUK, int NBLK,
        int* __restrict__ bhist, int* __restrict__ flags) {
    __shared__ int hist[256];
    __shared__ int sbuf[256];
    int t = threadIdx.x;
    int blk = blockIdx.x;
    int me = detect_me_block(ei, n, sbuf);
    if (blk == 0) {
        int mx = detect_mx_block(xidx, sbuf);
        if (t == 0) { flags[FLAG_ME] = me; flags[FLAG_MX] = mx; }
    }
    long long base = (long long)blk * CH;
    int cnt = (int)min((long long)CH, E - base);
    hist[t] = 0;
    __syncthreads();
    for (int i = t; i < cnt; i += 256) {
        int c = idx_at(ei, E + base + i, me);
        int b = min(c >> SH, NBUK - 1);
        atomicAdd(&hist[b], 1);
    }
    __syncthreads();
    if (t < NBUK) bhist[(size_t)t * NBLK + blk] = hist[t];
}

// P2a: per-bucket chunked LDS exclusive scan over block-counts (in place);
// gcount[b] = bucket total. Extra block (b == NBUK) converts W -> bf16 once.
__global__ void __launch_bounds__(256) k_p2a(
        int* __restrict__ bhist, int* __restrict__ gcount, int NBLK, int NBUK,
        const float* __restrict__ w, unsigned short* __restrict__ w8) {
    __shared__ int s[256];
    int b = blockIdx.x;
    int t = threadIdx.x;
    if (b >= NBUK) {  // W precompute: 64x64 fp32 -> bf16 (row-major [o][k])
        for (int i = t; i < 4096; i += 256) w8[i] = f2bf(w[i]);
        return;
    }
    int* row = bhist + (size_t)b * NBLK;
    int carry = 0;
    for (int base = 0; base < NBLK; base += 256) {
        int i = base + t;
        int v = (i < NBLK) ? row[i] : 0;
        s[t] = v;
        __syncthreads();
        for (int st = 1; st < 256; st <<= 1) {
            int add = (t >= st) ? s[t - st] : 0;
            __syncthreads();
            s[t] += add;
            __syncthreads();
        }
        if (i < NBLK) row[i] = carry + s[t] - v;  // exclusive
        int total = s[255];
        __syncthreads();
        carry += total;
    }
    if (t == 0) gcount[b] = carry;
}

// in-block exclusive scan of gcount (NBUK <= 256), 256-thread version.
__device__ void scan_gcount(const int* gcount, int NBUK, int* p, int* gb_ex) {
    int t = threadIdx.x;
    int v = (t < NBUK) ? gcount[t] : 0;
    p[t] = v;
    __syncthreads();
    for (int st = 1; st < 256; st <<= 1) {
        int add = (t >= st) ? p[t - st] : 0;
        __syncthreads();
        p[t] += add;
        __syncthreads();
    }
    gb_ex[t] = p[t] - v;
    __syncthreads();
}

// 512-thread version (threads >= 256 ride along through the syncs).
__device__ void scan_gcount_512(const int* gcount, int NBUK, int* p, int* gb_ex) {
    int t = threadIdx.x;
    int v = (t < 256) ? ((t < NBUK) ? gcount[t] : 0) : 0;
    if (t < 256) p[t] = v;
    __syncthreads();
    for (int st = 1; st < 256; st <<= 1) {
        int add = (t >= st && t < 256) ? p[t - st] : 0;
        __syncthreads();
        if (t < 256) p[t] += add;
        __syncthreads();
    }
    if (t < 256) gb_ex[t] = p[t] - v;
    __syncthreads();
}

// P3: block-local counting sort by bucket; write packed (r | clocal<<23)
// to bucket-major staging (4B/edge). Zero global atomics.
__global__ void __launch_bounds__(256) k_p3(
        const void* __restrict__ ei, long long E, int n, int NBUK, int NBLK,
        const int* __restrict__ bhist, const int* __restrict__ gcount,
        unsigned* __restrict__ gstag, const int* __restrict__ flags) {
    __shared__ int hist[256], lbase[256], rsv[256], lcur[256], s[256], gb[256];
    __shared__ unsigned stage[CH];
    int t = threadIdx.x;
    int blk = blockIdx.x;
    scan_gcount(gcount, NBUK, s, gb);
    long long base = (long long)blk * CH;
    int cnt = (int)min((long long)CH, E - base);
    int me = flags[FLAG_ME];
    hist[t] = 0;
    __syncthreads();
    for (int i = t; i < cnt; i += 256) {
        int c = idx_at(ei, E + base + i, me);
        atomicAdd(&hist[min(c >> SH, NBUK - 1)], 1);
    }
    __syncthreads();
    int v = hist[t];
    s[t] = v;
    __syncthreads();
    for (int st = 1; st < 256; st <<= 1) {
        int add = (t >= st) ? s[t - st] : 0;
        __syncthreads();
        s[t] += add;
        __syncthreads();
    }
    lbase[t] = s[t] - v;
    lcur[t] = s[t] - v;
    if (t < NBUK) rsv[t] = gb[t] + bhist[(size_t)t * NBLK + blk];
    __syncthreads();
    for (int i = t; i < cnt; i += 256) {
        long long e = base + i;
        int r = idx_at(ei, e, me);
        int c = idx_at(ei, E + e, me);
        int b = min(c >> SH, NBUK - 1);
        unsigned pkv = ((unsigned)r & RMASK) |
                       (((unsigned)(c - (b << SH)) & (WC - 1)) << 23);
        int slot = atomicAdd(&lcur[b], 1);
        stage[slot] = pkv;
    }
    __syncthreads();
    // slot i belongs to bucket b where lbase[b] <= i < lbase[b]+hist[b]
    for (int i = t; i < cnt; i += 256) {
        unsigned pkv = stage[i];
        int lo = 0, hi = NBUK - 1;
        while (lo < hi) {
            int mid = (lo + hi + 1) >> 1;
            if (lbase[mid] <= i) lo = mid; else hi = mid - 1;
        }
        gstag[rsv[lo] + (i - lbase[lo])] = pkv;
    }
}

// P4 (512 threads): one block per bucket: col histogram + scan -> off/dinv;
// rowidx placement into the bucket's contiguous slice; then per-node
// insertion sort of the segment by source id (enables sliced hops).
__global__ void __launch_bounds__(512) k_p4(
        const unsigned* __restrict__ gstag, const int* __restrict__ gcount,
        int* __restrict__ off, float* __restrict__ dinv,
        int* __restrict__ rowidx, int n, int NBUK) {
    __shared__ int hist[WC], lofs[WC], cur[WC], p[512], gb[256];
    int t = threadIdx.x;  // 0..511
    int b = blockIdx.x;
    int cbase = b << SH;
    scan_gcount_512(gcount, NBUK, p, gb);
    int e0 = gb[b];
    int e1 = e0 + gcount[b];
    int cnt = e1 - e0;
    if (b == NBUK - 1 && t == 0) off[n] = e1;  // == E
    hist[t] = 0;
    __syncthreads();
    for (int i = t; i < cnt; i += 512) {
        atomicAdd(&hist[gstag[e0 + i] >> 23], 1);
    }
    __syncthreads();
    // 512-wide exclusive scan, 1 elem/thread
    int v = hist[t];
    p[t] = v;
    __syncthreads();
    for (int st = 1; st < 512; st <<= 1) {
        int add = (t >= st) ? p[t - st] : 0;
        __syncthreads();
        p[t] += add;
        __syncthreads();
    }
    int excl = p[t] - v;
    lofs[t] = excl;
    cur[t] = excl;
    __syncthreads();
    int ncols = n - cbase;
    if (ncols < 0) ncols = 0;
    if (ncols > WC) ncols = WC;
    if (t < ncols) {
        off[cbase + t] = e0 + lofs[t];
        dinv[cbase + t] = rsqrtf((float)(hist[t] + 1));  // +1 self-loop
    }
    for (int i = t; i < cnt; i += 512) {
        unsigned pkv = gstag[e0 + i];
        int cl = (int)(pkv >> 23);
        int slot = atomicAdd(&cur[cl], 1);
        rowidx[e0 + slot] = (int)(pkv & RMASK);
    }
    __syncthreads();  // drains global writes (barrier implies vmcnt drain)
    // per-node insertion sort by source id; segments are small (~E/n) and
    // L2-hot (just written). hist/lofs intact (cur was the mutated copy).
    if (t < ncols) {
        int s0 = e0 + lofs[t];
        int s1 = s0 + hist[t];
        for (int i = s0 + 1; i < s1; i++) {
            int key = rowidx[i];
            int j = i - 1;
            while (j >= s0 && rowidx[j] > key) {
                rowidx[j + 1] = rowidx[j];
                j--;
            }
            rowidx[j + 1] = key;
        }
    }
}

// z0: z[node] = emb[xidx[node]] * dinv[node], bf16 out; thread = 16B chunk.
__global__ void __launch_bounds__(256) k_z0(
        const void* __restrict__ xidx, const float4* __restrict__ emb4,
        const float* __restrict__ dinv, uint4* __restrict__ z, int n,
        const int* __restrict__ flags) {
    int i = blockIdx.x * 256 + threadIdx.x;
    if (i >= n * 8) return;
    int node = i >> 3, q = i & 7;
    int xi = idx_at(xidx, node, flags[FLAG_MX]);
    if ((unsigned)xi >= (unsigned)n) xi = 0;
    float d = dinv[node];
    float4 a = emb4[(long long)xi * 16 + q * 2];
    float4 b = emb4[(long long)xi * 16 + q * 2 + 1];
    uint4 o;
    o.x = pk(a.x * d, a.y * d);
    o.y = pk(a.z * d, a.w * d);
    o.z = pk(b.x * d, b.y * d);
    o.w = pk(b.z * d, b.w * d);
    z[(long long)node * 8 + q] = o;
}

__device__ inline void acc8(float* acc, uint4 s) {
    acc[0] += bflo(s.x); acc[1] += bfhi(s.x);
    acc[2] += bflo(s.y); acc[3] += bfhi(s.y);
    acc[4] += bflo(s.z); acc[5] += bfhi(s.z);
    acc[6] += bflo(s.w); acc[7] += bfhi(s.w);
}

// Source-sliced hop body: edge lists sorted by source; sweep npass slices
// so concurrent waves gather from an L2-resident ~3MB window of zin.
// Self-loop folded into its slice's pass. Returns acc (caller scales).
__device__ inline void hop_body(
        float* acc, const uint4* __restrict__ zin,
        const int* __restrict__ rowidx, int e, int e1,
        int node, int q, int n, int npass) {
#pragma unroll 8
    for (int i = 0; i < 8; i++) acc[i] = 0.f;
    int prev = 0;
    for (int pass = 0; pass < npass; pass++) {
        int bound = (pass == npass - 1)
                        ? n
                        : (int)(((long long)(pass + 1) * n) / npass);
        if (node >= prev && node < bound) {
            uint4 s = zin[(long long)node * 8 + q];  // self-loop, in-slice
            acc8(acc, s);
        }
        while (e < e1) {
            if (e + 4 <= e1) {
                int r3 = __builtin_nontemporal_load(rowidx + e + 3);
                if (r3 < bound) {  // sorted: r3 is the batch max
                    int r0 = __builtin_nontemporal_load(rowidx + e + 0);
                    int r1 = __builtin_nontemporal_load(rowidx + e + 1);
                    int r2 = __builtin_nontemporal_load(rowidx + e + 2);
                    uint4 s0 = zin[(long long)r0 * 8 + q];
                    uint4 s1 = zin[(long long)r1 * 8 + q];
                    uint4 s2 = zin[(long long)r2 * 8 + q];
                    uint4 s3 = zin[(long long)r3 * 8 + q];
                    acc8(acc, s0);
                    acc8(acc, s1);
                    acc8(acc, s2);
                    acc8(acc, s3);
                    e += 4;
                    continue;
                }
            }
            int r = __builtin_nontemporal_load(rowidx + e);
            if (r >= bound) break;
            acc8(acc, zin[(long long)r * 8 + q]);
            e++;
        }
        prev = bound;
    }
}

// hop: 8 contiguous nodes per wave; lane = one 16B chunk (8 bf16).
// Mid hops only (scale d*d). zout store nontemporal (protect L2 slice).
__global__ void __launch_bounds__(256) k_hop(
        const uint4* __restrict__ zin, uint4* __restrict__ zout,
        const float* __restrict__ dinv, const int* __restrict__ off,
        const int* __restrict__ rowidx, int n, int npass) {
    int tid = blockIdx.x * 256 + threadIdx.x;
    int node = tid >> 3;
    int q = tid & 7;
    if (node >= n) return;
    int e0 = off[node], e1 = off[node + 1];
    float acc[8];
    hop_body(acc, zin, rowidx, e0, e1, node, q, n, npass);
    float d = dinv[node];
    float sc = d * d;
    uint32x4 o;
    o[0] = pk(acc[0] * sc, acc[1] * sc);
    o[1] = pk(acc[2] * sc, acc[3] * sc);
    o[2] = pk(acc[4] * sc, acc[5] * sc);
    o[3] = pk(acc[6] * sc, acc[7] * sc);
    __builtin_nontemporal_store(
        o, (uint32x4*)&zout[(long long)node * 8 + q]);
}

// Fused hop3 (scale d, last hop) + MFMA linear. One block = 32 nodes.
// Phase A: sliced hop loop, pack z3 -> swizzled 4KB LDS tile.
// Phase B: 4 waves x (1 M-tile of 16 nodes, 2 N-tiles of 16 cols) MFMA
// from LDS A-fragments + precomputed bf16 W (w8).
__global__ void __launch_bounds__(256) k_hop3_lin(
        const uint4* __restrict__ zin, const float* __restrict__ dinv,
        const int* __restrict__ off, const int* __restrict__ rowidx,
        const unsigned short* __restrict__ w8, const float* __restrict__ bias,
        float* __restrict__ out, int n, int npass) {
    __shared__ uint4 z3[32][8];  // [local node][16B chunk], chunk XOR-swizzled
    int t = threadIdx.x;
    int l = t >> 3;                      // local node 0..31
    int q = t & 7;                       // 16B chunk 0..7
    int node = blockIdx.x * 32 + l;
    uint4 o = {0u, 0u, 0u, 0u};          // pad nodes contribute zeros to MFMA
    if (node < n) {
        int e0 = off[node], e1 = off[node + 1];
        float acc[8];
        hop_body(acc, zin, rowidx, e0, e1, node, q, n, npass);
        float d = dinv[node];  // last hop: single dinv
        o.x = pk(acc[0] * d, acc[1] * d);
        o.y = pk(acc[2] * d, acc[3] * d);
        o.z = pk(acc[4] * d, acc[5] * d);
        o.w = pk(acc[6] * d, acc[7] * d);
    }
    z3[l][q ^ (l & 7)] = o;  // swizzle: breaks the 128B-stride bank conflict
    __syncthreads();

    // Phase B: lane/wave decomposition identical to old k_lin_mfma layout.
    int lane = t & 63, wv = t >> 6;
    int tile = wv >> 1;                  // 0..1: M-tile within block
    int nh = wv & 1;                     // 0..1: which pair of N-tiles
    int col = lane & 15, quad = lane >> 4;
    int node0 = blockIdx.x * 32 + tile * 16;
    int ln = tile * 16 + col;            // local node for A fragment
    short8 a[2];
#pragma unroll
    for (int s = 0; s < 2; s++) {
        int c = s * 4 + quad;
        a[s] = *(const short8*)&z3[ln][c ^ (ln & 7)];
    }
    const short8* wp = (const short8*)w8;  // [64 rows][8 chunks of 8 bf16]
#pragma unroll
    for (int j = 0; j < 2; j++) {
        int tN = nh * 2 + j;
        float bv = bias[tN * 16 + col];
        f32x4 acc4 = {bv, bv, bv, bv};
        acc4 = __builtin_amdgcn_mfma_f32_16x16x32_bf16(
            a[0], wp[(tN * 16 + col) * 8 + 0 * 4 + quad], acc4, 0, 0, 0);
        acc4 = __builtin_amdgcn_mfma_f32_16x16x32_bf16(
            a[1], wp[(tN * 16 + col) * 8 + 1 * 4 + quad], acc4, 0, 0, 0);
#pragma unroll
        for (int r = 0; r < 4; r++) {
            int nd = node0 + quad * 4 + r;
            if (nd < n) out[(size_t)nd * 64 + tN * 16 + col] = acc4[r];
        }
    }
}

extern "C" void kernel_launch(void* const* d_in, const int* in_sizes, int n_in,
                              void* d_out, int out_size, void* d_ws, size_t ws_size,
                              hipStream_t stream) {
    const void* xidx = d_in[0];
    const void* ei = d_in[1];
    const float* emb = (const float*)d_in[2];
    const float* w = (const float*)d_in[3];
    const float* b = (const float*)d_in[4];

    const int n = in_sizes[0];
    const long long E = in_sizes[1] / 2;
    int NBUK = (int)((n + WC - 1) >> SH);
    if (NBUK > 256) NBUK = 256;  // dataset: n=100k -> 196
    const int NBLK = (int)((E + CH - 1) / CH);

    // slice target ~3.2MB of z (128B/node) per pass -> 25600 nodes/slice
    int npass = (n + 25599) / 25600;
    if (npass < 1) npass = 1;

    char* p = (char*)d_ws;
    auto alloc = [&](size_t bytes) -> void* {
        void* r = (void*)p;
        p += (bytes + 255) & ~(size_t)255;
        return r;
    };
    int* flags = (int*)alloc(256);
    float* dinv = (float*)alloc((size_t)n * 4);
    int* off = (int*)alloc((size_t)(n + 1) * 4);
    int* gcount = (int*)alloc(257 * 4);
    int* bhist = (int*)alloc((size_t)NBLK * NBUK * 4);
    int* rowidx = (int*)alloc((size_t)E * 4);
    uint4* zA = (uint4*)alloc((size_t)n * 64 * 2);       // bf16 z (12.8 MB)
    unsigned short* w8 = (unsigned short*)alloc(4096 * 2);  // bf16 W
    uint4* zS = (uint4*)d_out;                           // bf16 z in d_out 1st half

    // packed staging (4B/edge) in d_out's 2nd half (E*4 <= n*64*2 here)
    unsigned* gstag;
    if ((size_t)E * 4 <= (size_t)n * 64 * 2)
        gstag = (unsigned*)((char*)d_out + (size_t)n * 64 * 2);
    else
        gstag = (unsigned*)alloc((size_t)E * 4);

    k_p1<<<NBLK, 256, 0, stream>>>(ei, xidx, E, n, NBUK, NBLK, bhist, flags);
    k_p2a<<<NBUK + 1, 256, 0, stream>>>(bhist, gcount, NBLK, NBUK, w, w8);
    k_p3<<<NBLK, 256, 0, stream>>>(ei, E, n, NBUK, NBLK, bhist, gcount, gstag, flags);
    k_p4<<<NBUK, 512, 0, stream>>>(gstag, gcount, off, dinv, rowidx, n, NBUK);

    const int gF = (n * 8 + 255) / 256;
    const int gL = (n + 31) / 32;

    // z0 -> zA(ws); hop1 zA->zS(d_out); hop2 zS->zA; fused hop3+lin zA -> d_out.
    // (fused kernel writes d_out; its gather input zA is workspace -> no race)
    k_z0<<<gF, 256, 0, stream>>>(xidx, (const float4*)emb, dinv, zA, n, flags);
    k_hop<<<gF, 256, 0, stream>>>(zA, zS, dinv, off, rowidx, n, npass);
    k_hop<<<gF, 256, 0, stream>>>(zS, zA, dinv, off, rowidx, n, npass);
    k_hop3_lin<<<gL, 256, 0, stream>>>(zA, dinv, off, rowidx, w8, b,
                                       (float*)d_out, n, npass);
}

// Round 6
// 299.175 us; speedup vs baseline: 1.5480x; 1.5480x over previous
//
#include <hip/hip_runtime.h>
#include <hip/hip_bf16.h>
#include <math.h>

// SGConv: x = emb[x_indices]; 3 hops of D^-1/2 (A+I) D^-1/2; out = x3 @ W^T + b.
// z-space: z = dinv*x; hop: z' = dinv^2*(z[c] + sum_{r->c} z[r]); last hop dinv^1.
// LEDGER (verified r0-18): emb/w/b fp32, out fp32, ei contiguous (2,E),
// index widths runtime-classified, bf16 z validated (absmax 4.9e-4).
// r17: un-fuse z0 from p4. r18: W-precompute + fused hop3+linear (250.5us).
// r19 FAILED (463us): insertion sort in p4 = 124us (O(k^2) serialized global
// traffic); nontemporal rowidx loads put ~900cy misses on the gather critical
// path (~+30us/hop). Theory (L2-sliced gathers) never cleanly measured.
// r20 (2nd resubmit — two GPUAcquisitionTimeouts, never ran):
// decomposed retry. (a) p4 slice-binned counting sort: 2048 LDS bins
// (col*npass+slice) -> edge segments slice-GROUPED for free, no sort, p4
// back to r18 cost. Slice-grouped is sufficient for hop's monotone bound
// checks (r3<bound => r0..r2<bound). (b) hops: plain loads/stores (NO
// nontemporal), unroll-4 core, npass=4 slice sweep so resident waves gather
// from a 3.2MB L2-resident z window. Clean A/B on slicing.

#define FLAG_MX 0
#define FLAG_ME 1
#define SH 9        // 512 cols per bucket
#define WC 512      // cols per bucket
#define CH 4096     // edges per P1/P3 block
#define NP 4        // max source slices (bins = WC*NP = 2048)
#define RMASK 0x7FFFFFu

using short8 = __attribute__((ext_vector_type(8))) short;
using f32x4 = __attribute__((ext_vector_type(4))) float;

__device__ inline int idx_at(const void* p, long long i, int mode) {
    switch (mode) {
        case 1: return (int)((const long long*)p)[i];
        case 2: return (int)((const float*)p)[i];
        case 3: return (int)((const double*)p)[i];
        default: return ((const int*)p)[i];
    }
}

// bf16 helpers (RNE pack, shift unpack)
__device__ inline unsigned short f2bf(float f) {
    union { float f; unsigned u; } v; v.f = f;
    unsigned r = v.u + 0x7FFFu + ((v.u >> 16) & 1u);
    return (unsigned short)(r >> 16);
}
__device__ inline float bflo(unsigned d) { union { unsigned u; float f; } v; v.u = d << 16; return v.f; }
__device__ inline float bfhi(unsigned d) { union { unsigned u; float f; } v; v.u = d & 0xFFFF0000u; return v.f; }
__device__ inline unsigned pk(float a, float b) {
    return (unsigned)f2bf(a) | ((unsigned)f2bf(b) << 16);
}

// slice boundaries: bound(p) = ((p+1)*n)/npass; slice(r) = p s.t.
// bound(p-1) <= r < bound(p). floor-div estimate + adjust (<=1 step).
__device__ inline int slice_of(int r, int n, int npass) {
    int sl = (int)(((long long)r * npass) / n);
    if (sl >= npass) sl = npass - 1;
    while (r >= (int)(((long long)(sl + 1) * n) / npass) && sl < npass - 1) sl++;
    while (sl > 0 && r < (int)(((long long)sl * n) / npass)) sl--;
    return sl;
}

__device__ int detect_me_block(const void* ei, int n, int* sbuf) {
    int t = threadIdx.x;
    int oke = 15;
    const int* w = (const int*)ei;
    const long long* L = (const long long*)ei;
    const float* f = (const float*)ei;
    const double* d = (const double*)ei;
    for (int k = t; k < 2048; k += 256) {
        if (!((unsigned)w[k] < (unsigned)n)) oke &= ~1;
        long long lv = L[k];
        if (!(lv >= 0 && lv < (long long)n)) oke &= ~2;
        float fv = f[k];
        if (!(fv >= 0.f && fv < (float)n && fv == truncf(fv))) oke &= ~4;
        double dv = d[k];
        if (!(dv >= 0.0 && dv < (double)n && dv == trunc(dv))) oke &= ~8;
    }
    sbuf[t] = oke;
    __syncthreads();
    for (int st = 128; st; st >>= 1) {
        if (t < st) sbuf[t] &= sbuf[t + st];
        __syncthreads();
    }
    int r = sbuf[0];
    __syncthreads();
    return (r & 2) ? 1 : (r & 8) ? 3 : (r & 4) ? 2 : 0;
}

__device__ int detect_mx_block(const void* xidx, int* sbuf) {
    int t = threadIdx.x;
    int okx = 15;
    const int* w = (const int*)xidx;
    const long long* L = (const long long*)xidx;
    const float* f = (const float*)xidx;
    const double* d = (const double*)xidx;
    for (int k = t; k < 2048; k += 256) {
        if (w[k] != k) okx &= ~1;
        if (L[k] != (long long)k) okx &= ~2;
        if (!(f[k] == (float)k)) okx &= ~4;
        if (!(d[k] == (double)k)) okx &= ~8;
    }
    sbuf[t] = okx;
    __syncthreads();
    for (int st = 128; st; st >>= 1) {
        if (t < st) sbuf[t] &= sbuf[t + st];
        __syncthreads();
    }
    int r = sbuf[0];
    __syncthreads();
    return (r & 2) ? 1 : (r & 8) ? 3 : (r & 4) ? 2 : 0;
}

// P1: inline classify (block 0 publishes flags) + per-block bucket histogram
// -> bhist[b*NBLK + blk] (bucket-major).
__global__ void __launch_bounds__(256) k_p1(
        const void* __restrict__ ei, const void* __restrict__ xidx,
        long long E, int n, int NBUK, int NBLK,
        int* __restrict__ bhist, int* __restrict__ flags) {
    __shared__ int hist[256];
    __shared__ int sbuf[256];
    int t = threadIdx.x;
    int blk = blockIdx.x;
    int me = detect_me_block(ei, n, sbuf);
    if (blk == 0) {
        int mx = detect_mx_block(xidx, sbuf);
        if (t == 0) { flags[FLAG_ME] = me; flags[FLAG_MX] = mx; }
    }
    long long base = (long long)blk * CH;
    int cnt = (int)min((long long)CH, E - base);
    hist[t] = 0;
    __syncthreads();
    for (int i = t; i < cnt; i += 256) {
        int c = idx_at(ei, E + base + i, me);
        int b = min(c >> SH, NBUK - 1);
        atomicAdd(&hist[b], 1);
    }
    __syncthreads();
    if (t < NBUK) bhist[(size_t)t * NBLK + blk] = hist[t];
}

// P2a: per-bucket chunked LDS exclusive scan over block-counts (in place);
// gcount[b] = bucket total. Extra block (b == NBUK) converts W -> bf16 once.
__global__ void __launch_bounds__(256) k_p2a(
        int* __restrict__ bhist, int* __restrict__ gcount, int NBLK, int NBUK,
        const float* __restrict__ w, unsigned short* __restrict__ w8) {
    __shared__ int s[256];
    int b = blockIdx.x;
    int t = threadIdx.x;
    if (b >= NBUK) {  // W precompute: 64x64 fp32 -> bf16 (row-major [o][k])
        for (int i = t; i < 4096; i += 256) w8[i] = f2bf(w[i]);
        return;
    }
    int* row = bhist + (size_t)b * NBLK;
    int carry = 0;
    for (int base = 0; base < NBLK; base += 256) {
        int i = base + t;
        int v = (i < NBLK) ? row[i] : 0;
        s[t] = v;
        __syncthreads();
        for (int st = 1; st < 256; st <<= 1) {
            int add = (t >= st) ? s[t - st] : 0;
            __syncthreads();
            s[t] += add;
            __syncthreads();
        }
        if (i < NBLK) row[i] = carry + s[t] - v;  // exclusive
        int total = s[255];
        __syncthreads();
        carry += total;
    }
    if (t == 0) gcount[b] = carry;
}

// in-block exclusive scan of gcount (NBUK <= 256), 256-thread version.
__device__ void scan_gcount(const int* gcount, int NBUK, int* p, int* gb_ex) {
    int t = threadIdx.x;
    int v = (t < NBUK) ? gcount[t] : 0;
    p[t] = v;
    __syncthreads();
    for (int st = 1; st < 256; st <<= 1) {
        int add = (t >= st) ? p[t - st] : 0;
        __syncthreads();
        p[t] += add;
        __syncthreads();
    }
    gb_ex[t] = p[t] - v;
    __syncthreads();
}

// 512-thread version (threads >= 256 ride along through the syncs).
__device__ void scan_gcount_512(const int* gcount, int NBUK, int* p, int* gb_ex) {
    int t = threadIdx.x;
    int v = (t < 256) ? ((t < NBUK) ? gcount[t] : 0) : 0;
    if (t < 256) p[t] = v;
    __syncthreads();
    for (int st = 1; st < 256; st <<= 1) {
        int add = (t >= st && t < 256) ? p[t - st] : 0;
        __syncthreads();
        if (t < 256) p[t] += add;
        __syncthreads();
    }
    if (t < 256) gb_ex[t] = p[t] - v;
    __syncthreads();
}

// P3: block-local counting sort by bucket; write packed (r | clocal<<23)
// to bucket-major staging (4B/edge). Zero global atomics.
__global__ void __launch_bounds__(256) k_p3(
        const void* __restrict__ ei, long long E, int n, int NBUK, int NBLK,
        const int* __restrict__ bhist, const int* __restrict__ gcount,
        unsigned* __restrict__ gstag, const int* __restrict__ flags) {
    __shared__ int hist[256], lbase[256], rsv[256], lcur[256], s[256], gb[256];
    __shared__ unsigned stage[CH];
    int t = threadIdx.x;
    int blk = blockIdx.x;
    scan_gcount(gcount, NBUK, s, gb);
    long long base = (long long)blk * CH;
    int cnt = (int)min((long long)CH, E - base);
    int me = flags[FLAG_ME];
    hist[t] = 0;
    __syncthreads();
    for (int i = t; i < cnt; i += 256) {
        int c = idx_at(ei, E + base + i, me);
        atomicAdd(&hist[min(c >> SH, NBUK - 1)], 1);
    }
    __syncthreads();
    int v = hist[t];
    s[t] = v;
    __syncthreads();
    for (int st = 1; st < 256; st <<= 1) {
        int add = (t >= st) ? s[t - st] : 0;
        __syncthreads();
        s[t] += add;
        __syncthreads();
    }
    lbase[t] = s[t] - v;
    lcur[t] = s[t] - v;
    if (t < NBUK) rsv[t] = gb[t] + bhist[(size_t)t * NBLK + blk];
    __syncthreads();
    for (int i = t; i < cnt; i += 256) {
        long long e = base + i;
        int r = idx_at(ei, e, me);
        int c = idx_at(ei, E + e, me);
        int b = min(c >> SH, NBUK - 1);
        unsigned pkv = ((unsigned)r & RMASK) |
                       (((unsigned)(c - (b << SH)) & (WC - 1)) << 23);
        int slot = atomicAdd(&lcur[b], 1);
        stage[slot] = pkv;
    }
    __syncthreads();
    // slot i belongs to bucket b where lbase[b] <= i < lbase[b]+hist[b]
    for (int i = t; i < cnt; i += 256) {
        unsigned pkv = stage[i];
        int lo = 0, hi = NBUK - 1;
        while (lo < hi) {
            int mid = (lo + hi + 1) >> 1;
            if (lbase[mid] <= i) lo = mid; else hi = mid - 1;
        }
        gstag[rsv[lo] + (i - lbase[lo])] = pkv;
    }
}

// P4 (512 threads): one block per bucket. Slice-binned counting sort:
// 2048 bins (col*npass + source-slice) -> per-col segments slice-GROUPED
// (sufficient for sliced hop's monotone bound checks). No insertion sort.
__global__ void __launch_bounds__(512) k_p4(
        const unsigned* __restrict__ gstag, const int* __restrict__ gcount,
        int* __restrict__ off, float* __restrict__ dinv,
        int* __restrict__ rowidx, int n, int NBUK, int npass) {
    __shared__ int hist[WC * NP];  // 8KB: histogram, then in-place cursors
    __shared__ int p[512], gb[256];
    int t = threadIdx.x;  // 0..511 (== WC, one col per thread)
    int b = blockIdx.x;
    int cbase = b << SH;
    scan_gcount_512(gcount, NBUK, p, gb);
    int e0 = gb[b];
    int e1 = e0 + gcount[b];
    int cnt = e1 - e0;
    if (b == NBUK - 1 && t == 0) off[n] = e1;  // == E
    for (int i = t; i < WC * NP; i += 512) hist[i] = 0;
    __syncthreads();
    for (int i = t; i < cnt; i += 512) {
        unsigned pkv = gstag[e0 + i];
        int cl = (int)(pkv >> 23);
        int r = (int)(pkv & RMASK);
        atomicAdd(&hist[cl * npass + slice_of(r, n, npass)], 1);
    }
    __syncthreads();
    // per-col total (thread t owns col t's npass contiguous bins)
    int lsum = 0;
#pragma unroll
    for (int s = 0; s < NP; s++)
        if (s < npass) lsum += hist[t * npass + s];
    // 512-wide exclusive scan of col totals
    p[t] = lsum;
    __syncthreads();
    for (int st = 1; st < 512; st <<= 1) {
        int add = (t >= st) ? p[t - st] : 0;
        __syncthreads();
        p[t] += add;
        __syncthreads();
    }
    int excl = p[t] - lsum;
    // convert hist -> in-place exclusive cursors; publish off/dinv
    {
        int run = excl;
#pragma unroll
        for (int s = 0; s < NP; s++) {
            if (s < npass) {
                int h = hist[t * npass + s];
                hist[t * npass + s] = run;
                run += h;
            }
        }
    }
    int ncols = n - cbase;
    if (ncols < 0) ncols = 0;
    if (ncols > WC) ncols = WC;
    if (t < ncols) {
        off[cbase + t] = e0 + excl;
        dinv[cbase + t] = rsqrtf((float)(lsum + 1));  // +1 self-loop
    }
    __syncthreads();
    for (int i = t; i < cnt; i += 512) {
        unsigned pkv = gstag[e0 + i];
        int cl = (int)(pkv >> 23);
        int r = (int)(pkv & RMASK);
        int slot = atomicAdd(&hist[cl * npass + slice_of(r, n, npass)], 1);
        rowidx[e0 + slot] = r;
    }
}

// z0: z[node] = emb[xidx[node]] * dinv[node], bf16 out; thread = 16B chunk.
__global__ void __launch_bounds__(256) k_z0(
        const void* __restrict__ xidx, const float4* __restrict__ emb4,
        const float* __restrict__ dinv, uint4* __restrict__ z, int n,
        const int* __restrict__ flags) {
    int i = blockIdx.x * 256 + threadIdx.x;
    if (i >= n * 8) return;
    int node = i >> 3, q = i & 7;
    int xi = idx_at(xidx, node, flags[FLAG_MX]);
    if ((unsigned)xi >= (unsigned)n) xi = 0;
    float d = dinv[node];
    float4 a = emb4[(long long)xi * 16 + q * 2];
    float4 b = emb4[(long long)xi * 16 + q * 2 + 1];
    uint4 o;
    o.x = pk(a.x * d, a.y * d);
    o.y = pk(a.z * d, a.w * d);
    o.z = pk(b.x * d, b.y * d);
    o.w = pk(b.z * d, b.w * d);
    z[(long long)node * 8 + q] = o;
}

__device__ inline void acc8(float* acc, uint4 s) {
    acc[0] += bflo(s.x); acc[1] += bfhi(s.x);
    acc[2] += bflo(s.y); acc[3] += bfhi(s.y);
    acc[4] += bflo(s.z); acc[5] += bfhi(s.z);
    acc[6] += bflo(s.w); acc[7] += bfhi(s.w);
}

// Source-sliced hop body: edge lists slice-grouped by source; sweep npass
// slices so concurrent waves gather from an L2-resident ~3MB zin window.
// Plain loads (rowidx stays L1/L2-hot on the critical path — r19 lesson).
__device__ inline void hop_body(
        float* acc, const uint4* __restrict__ zin,
        const int* __restrict__ rowidx, int e, int e1,
        int node, int q, int n, int npass) {
#pragma unroll 8
    for (int i = 0; i < 8; i++) acc[i] = 0.f;
    int prev = 0;
    for (int pass = 0; pass < npass; pass++) {
        int bound = (pass == npass - 1)
                        ? n
                        : (int)(((long long)(pass + 1) * n) / npass);
        if (node >= prev && node < bound) {
            uint4 s = zin[(long long)node * 8 + q];  // self-loop, in-slice
            acc8(acc, s);
        }
        for (; e + 4 <= e1; ) {
            int r3 = rowidx[e + 3];
            if (r3 >= bound) break;  // slice-grouped: r3 >= r0..r2's slices
            int r0 = rowidx[e + 0];
            int r1 = rowidx[e + 1];
            int r2 = rowidx[e + 2];
            uint4 s0 = zin[(long long)r0 * 8 + q];
            uint4 s1 = zin[(long long)r1 * 8 + q];
            uint4 s2 = zin[(long long)r2 * 8 + q];
            uint4 s3 = zin[(long long)r3 * 8 + q];
            acc8(acc, s0);
            acc8(acc, s1);
            acc8(acc, s2);
            acc8(acc, s3);
            e += 4;
        }
        while (e < e1) {
            int r = rowidx[e];
            if (r >= bound) break;
            acc8(acc, zin[(long long)r * 8 + q]);
            e++;
        }
        prev = bound;
    }
}

// hop: 8 contiguous nodes per wave; lane = one 16B chunk (8 bf16).
// Mid hops only (scale d*d).
__global__ void __launch_bounds__(256) k_hop(
        const uint4* __restrict__ zin, uint4* __restrict__ zout,
        const float* __restrict__ dinv, const int* __restrict__ off,
        const int* __restrict__ rowidx, int n, int npass) {
    int tid = blockIdx.x * 256 + threadIdx.x;
    int node = tid >> 3;
    int q = tid & 7;
    if (node >= n) return;
    int e0 = off[node], e1 = off[node + 1];
    float acc[8];
    hop_body(acc, zin, rowidx, e0, e1, node, q, n, npass);
    float d = dinv[node];
    float sc = d * d;
    uint4 o;
    o.x = pk(acc[0] * sc, acc[1] * sc);
    o.y = pk(acc[2] * sc, acc[3] * sc);
    o.z = pk(acc[4] * sc, acc[5] * sc);
    o.w = pk(acc[6] * sc, acc[7] * sc);
    zout[(long long)node * 8 + q] = o;
}

// Fused hop3 (scale d, last hop) + MFMA linear. One block = 32 nodes.
// Phase A: sliced hop loop, pack z3 -> swizzled 4KB LDS tile.
// Phase B: 4 waves x (1 M-tile of 16 nodes, 2 N-tiles of 16 cols) MFMA
// from LDS A-fragments + precomputed bf16 W (w8).
__global__ void __launch_bounds__(256) k_hop3_lin(
        const uint4* __restrict__ zin, const float* __restrict__ dinv,
        const int* __restrict__ off, const int* __restrict__ rowidx,
        const unsigned short* __restrict__ w8, const float* __restrict__ bias,
        float* __restrict__ out, int n, int npass) {
    __shared__ uint4 z3[32][8];  // [local node][16B chunk], chunk XOR-swizzled
    int t = threadIdx.x;
    int l = t >> 3;                      // local node 0..31
    int q = t & 7;                       // 16B chunk 0..7
    int node = blockIdx.x * 32 + l;
    uint4 o = {0u, 0u, 0u, 0u};          // pad nodes contribute zeros to MFMA
    if (node < n) {
        int e0 = off[node], e1 = off[node + 1];
        float acc[8];
        hop_body(acc, zin, rowidx, e0, e1, node, q, n, npass);
        float d = dinv[node];  // last hop: single dinv
        o.x = pk(acc[0] * d, acc[1] * d);
        o.y = pk(acc[2] * d, acc[3] * d);
        o.z = pk(acc[4] * d, acc[5] * d);
        o.w = pk(acc[6] * d, acc[7] * d);
    }
    z3[l][q ^ (l & 7)] = o;  // swizzle: breaks the 128B-stride bank conflict
    __syncthreads();

    // Phase B: lane/wave decomposition identical to old k_lin_mfma layout.
    int lane = t & 63, wv = t >> 6;
    int tile = wv >> 1;                  // 0..1: M-tile within block
    int nh = wv & 1;                     // 0..1: which pair of N-tiles
    int col = lane & 15, quad = lane >> 4;
    int node0 = blockIdx.x * 32 + tile * 16;
    int ln = tile * 16 + col;            // local node for A fragment
    short8 a[2];
#pragma unroll
    for (int s = 0; s < 2; s++) {
        int c = s * 4 + quad;
        a[s] = *(const short8*)&z3[ln][c ^ (ln & 7)];
    }
    const short8* wp = (const short8*)w8;  // [64 rows][8 chunks of 8 bf16]
#pragma unroll
    for (int j = 0; j < 2; j++) {
        int tN = nh * 2 + j;
        float bv = bias[tN * 16 + col];
        f32x4 acc4 = {bv, bv, bv, bv};
        acc4 = __builtin_amdgcn_mfma_f32_16x16x32_bf16(
            a[0], wp[(tN * 16 + col) * 8 + 0 * 4 + quad], acc4, 0, 0, 0);
        acc4 = __builtin_amdgcn_mfma_f32_16x16x32_bf16(
            a[1], wp[(tN * 16 + col) * 8 + 1 * 4 + quad], acc4, 0, 0, 0);
#pragma unroll
        for (int r = 0; r < 4; r++) {
            int nd = node0 + quad * 4 + r;
            if (nd < n) out[(size_t)nd * 64 + tN * 16 + col] = acc4[r];
        }
    }
}

extern "C" void kernel_launch(void* const* d_in, const int* in_sizes, int n_in,
                              void* d_out, int out_size, void* d_ws, size_t ws_size,
                              hipStream_t stream) {
    const void* xidx = d_in[0];
    const void* ei = d_in[1];
    const float* emb = (const float*)d_in[2];
    const float* w = (const float*)d_in[3];
    const float* b = (const float*)d_in[4];

    const int n = in_sizes[0];
    const long long E = in_sizes[1] / 2;
    int NBUK = (int)((n + WC - 1) >> SH);
    if (NBUK > 256) NBUK = 256;  // dataset: n=100k -> 196
    const int NBLK = (int)((E + CH - 1) / CH);

    // slice target ~3.2MB of z (128B/node) per pass; clamp to NP bins
    int npass = (n + 25599) / 25600;
    if (npass < 1) npass = 1;
    if (npass > NP) npass = NP;

    char* p = (char*)d_ws;
    auto alloc = [&](size_t bytes) -> void* {
        void* r = (void*)p;
        p += (bytes + 255) & ~(size_t)255;
        return r;
    };
    int* flags = (int*)alloc(256);
    float* dinv = (float*)alloc((size_t)n * 4);
    int* off = (int*)alloc((size_t)(n + 1) * 4);
    int* gcount = (int*)alloc(257 * 4);
    int* bhist = (int*)alloc((size_t)NBLK * NBUK * 4);
    int* rowidx = (int*)alloc((size_t)E * 4);
    uint4* zA = (uint4*)alloc((size_t)n * 64 * 2);       // bf16 z (12.8 MB)
    unsigned short* w8 = (unsigned short*)alloc(4096 * 2);  // bf16 W
    uint4* zS = (uint4*)d_out;                           // bf16 z in d_out 1st half

    // packed staging (4B/edge) in d_out's 2nd half (E*4 <= n*64*2 here)
    unsigned* gstag;
    if ((size_t)E * 4 <= (size_t)n * 64 * 2)
        gstag = (unsigned*)((char*)d_out + (size_t)n * 64 * 2);
    else
        gstag = (unsigned*)alloc((size_t)E * 4);

    k_p1<<<NBLK, 256, 0, stream>>>(ei, xidx, E, n, NBUK, NBLK, bhist, flags);
    k_p2a<<<NBUK + 1, 256, 0, stream>>>(bhist, gcount, NBLK, NBUK, w, w8);
    k_p3<<<NBLK, 256, 0, stream>>>(ei, E, n, NBUK, NBLK, bhist, gcount, gstag, flags);
    k_p4<<<NBUK, 512, 0, stream>>>(gstag, gcount, off, dinv, rowidx, n, NBUK, npass);

    const int gF = (n * 8 + 255) / 256;
    const int gL = (n + 31) / 32;

    // z0 -> zA(ws); hop1 zA->zS(d_out); hop2 zS->zA; fused hop3+lin zA -> d_out.
    // (fused kernel writes d_out; its gather input zA is workspace -> no race)
    k_z0<<<gF, 256, 0, stream>>>(xidx, (const float4*)emb, dinv, zA, n, flags);
    k_hop<<<gF, 256, 0, stream>>>(zA, zS, dinv, off, rowidx, n, npass);
    k_hop<<<gF, 256, 0, stream>>>(zS, zA, dinv, off, rowidx, n, npass);
    k_hop3_lin<<<gL, 256, 0, stream>>>(zA, dinv, off, rowidx, w8, b,
                                       (float*)d_out, n, npass);
}

// Round 7
// 254.565 us; speedup vs baseline: 1.8192x; 1.1752x over previous
//
#include <hip/hip_runtime.h>
#include <hip/hip_bf16.h>
#include <math.h>

// SGConv: x = emb[x_indices]; 3 hops of D^-1/2 (A+I) D^-1/2; out = x3 @ W^T + b.
// z-space: z = dinv*x; hop: z' = dinv^2*(z[c] + sum_{r->c} z[r]); last hop dinv^1.
// LEDGER (verified r0-18): emb/w/b fp32, out fp32, ei contiguous (2,E),
// index widths runtime-classified, bf16 z validated (absmax 4.9e-4).
// r18: W-precompute + fused hop3+linear = 250.5us (best).
// r19 FAILED (463us): p4 insertion sort O(k^2) + nontemporal rowidx.
// r20 FAILED (299us): source-sliced hops — FETCH 68.5MB on hop3_lin showed
// slicing does NOT localize L2 (blocks aren't pass-synchronized; working set
// stays all of z) and per-pass loop overhead+divergence cost ~10us/hop.
// Counters: MfmaUtil 0.6 / VALUBusy 35 / Occ 60 / L2-miss BW 1.3TB/s ->
// NO pipe saturated -> hops are LATENCY-bound, low MLP. Revised theory.
// r21 (this round): revert slicing (p4 = r18 counting sort, hop = plain
// unroll-4). Attack latency: 16 lanes/node — h=0/h=1 lanes each take half
// the edge list (halves the dependent-batch chain, doubles in-flight
// gathers, shortens divergence tail), combine via __shfl_xor(acc,8) once
// per node. hop3_lin: 16 nodes/block, phase B = 4 waves x one 16x16 N-tile.

#define FLAG_MX 0
#define FLAG_ME 1
#define SH 9        // 512 cols per bucket
#define WC 512      // cols per bucket
#define CH 4096     // edges per P1/P3 block
#define RMASK 0x7FFFFFu

using short8 = __attribute__((ext_vector_type(8))) short;
using f32x4 = __attribute__((ext_vector_type(4))) float;

__device__ inline int idx_at(const void* p, long long i, int mode) {
    switch (mode) {
        case 1: return (int)((const long long*)p)[i];
        case 2: return (int)((const float*)p)[i];
        case 3: return (int)((const double*)p)[i];
        default: return ((const int*)p)[i];
    }
}

// bf16 helpers (RNE pack, shift unpack)
__device__ inline unsigned short f2bf(float f) {
    union { float f; unsigned u; } v; v.f = f;
    unsigned r = v.u + 0x7FFFu + ((v.u >> 16) & 1u);
    return (unsigned short)(r >> 16);
}
__device__ inline float bflo(unsigned d) { union { unsigned u; float f; } v; v.u = d << 16; return v.f; }
__device__ inline float bfhi(unsigned d) { union { unsigned u; float f; } v; v.u = d & 0xFFFF0000u; return v.f; }
__device__ inline unsigned pk(float a, float b) {
    return (unsigned)f2bf(a) | ((unsigned)f2bf(b) << 16);
}

__device__ int detect_me_block(const void* ei, int n, int* sbuf) {
    int t = threadIdx.x;
    int oke = 15;
    const int* w = (const int*)ei;
    const long long* L = (const long long*)ei;
    const float* f = (const float*)ei;
    const double* d = (const double*)ei;
    for (int k = t; k < 2048; k += 256) {
        if (!((unsigned)w[k] < (unsigned)n)) oke &= ~1;
        long long lv = L[k];
        if (!(lv >= 0 && lv < (long long)n)) oke &= ~2;
        float fv = f[k];
        if (!(fv >= 0.f && fv < (float)n && fv == truncf(fv))) oke &= ~4;
        double dv = d[k];
        if (!(dv >= 0.0 && dv < (double)n && dv == trunc(dv))) oke &= ~8;
    }
    sbuf[t] = oke;
    __syncthreads();
    for (int st = 128; st; st >>= 1) {
        if (t < st) sbuf[t] &= sbuf[t + st];
        __syncthreads();
    }
    int r = sbuf[0];
    __syncthreads();
    return (r & 2) ? 1 : (r & 8) ? 3 : (r & 4) ? 2 : 0;
}

__device__ int detect_mx_block(const void* xidx, int* sbuf) {
    int t = threadIdx.x;
    int okx = 15;
    const int* w = (const int*)xidx;
    const long long* L = (const long long*)xidx;
    const float* f = (const float*)xidx;
    const double* d = (const double*)xidx;
    for (int k = t; k < 2048; k += 256) {
        if (w[k] != k) okx &= ~1;
        if (L[k] != (long long)k) okx &= ~2;
        if (!(f[k] == (float)k)) okx &= ~4;
        if (!(d[k] == (double)k)) okx &= ~8;
    }
    sbuf[t] = okx;
    __syncthreads();
    for (int st = 128; st; st >>= 1) {
        if (t < st) sbuf[t] &= sbuf[t + st];
        __syncthreads();
    }
    int r = sbuf[0];
    __syncthreads();
    return (r & 2) ? 1 : (r & 8) ? 3 : (r & 4) ? 2 : 0;
}

// P1: inline classify (block 0 publishes flags) + per-block bucket histogram
// -> bhist[b*NBLK + blk] (bucket-major).
__global__ void __launch_bounds__(256) k_p1(
        const void* __restrict__ ei, const void* __restrict__ xidx,
        long long E, int n, int NBUK, int NBLK,
        int* __restrict__ bhist, int* __restrict__ flags) {
    __shared__ int hist[256];
    __shared__ int sbuf[256];
    int t = threadIdx.x;
    int blk = blockIdx.x;
    int me = detect_me_block(ei, n, sbuf);
    if (blk == 0) {
        int mx = detect_mx_block(xidx, sbuf);
        if (t == 0) { flags[FLAG_ME] = me; flags[FLAG_MX] = mx; }
    }
    long long base = (long long)blk * CH;
    int cnt = (int)min((long long)CH, E - base);
    hist[t] = 0;
    __syncthreads();
    for (int i = t; i < cnt; i += 256) {
        int c = idx_at(ei, E + base + i, me);
        int b = min(c >> SH, NBUK - 1);
        atomicAdd(&hist[b], 1);
    }
    __syncthreads();
    if (t < NBUK) bhist[(size_t)t * NBLK + blk] = hist[t];
}

// P2a: per-bucket chunked LDS exclusive scan over block-counts (in place);
// gcount[b] = bucket total. Extra block (b == NBUK) converts W -> bf16 once.
__global__ void __launch_bounds__(256) k_p2a(
        int* __restrict__ bhist, int* __restrict__ gcount, int NBLK, int NBUK,
        const float* __restrict__ w, unsigned short* __restrict__ w8) {
    __shared__ int s[256];
    int b = blockIdx.x;
    int t = threadIdx.x;
    if (b >= NBUK) {  // W precompute: 64x64 fp32 -> bf16 (row-major [o][k])
        for (int i = t; i < 4096; i += 256) w8[i] = f2bf(w[i]);
        return;
    }
    int* row = bhist + (size_t)b * NBLK;
    int carry = 0;
    for (int base = 0; base < NBLK; base += 256) {
        int i = base + t;
        int v = (i < NBLK) ? row[i] : 0;
        s[t] = v;
        __syncthreads();
        for (int st = 1; st < 256; st <<= 1) {
            int add = (t >= st) ? s[t - st] : 0;
            __syncthreads();
            s[t] += add;
            __syncthreads();
        }
        if (i < NBLK) row[i] = carry + s[t] - v;  // exclusive
        int total = s[255];
        __syncthreads();
        carry += total;
    }
    if (t == 0) gcount[b] = carry;
}

// in-block exclusive scan of gcount (NBUK <= 256), 256-thread version.
__device__ void scan_gcount(const int* gcount, int NBUK, int* p, int* gb_ex) {
    int t = threadIdx.x;
    int v = (t < NBUK) ? gcount[t] : 0;
    p[t] = v;
    __syncthreads();
    for (int st = 1; st < 256; st <<= 1) {
        int add = (t >= st) ? p[t - st] : 0;
        __syncthreads();
        p[t] += add;
        __syncthreads();
    }
    gb_ex[t] = p[t] - v;
    __syncthreads();
}

// 512-thread version (threads >= 256 ride along through the syncs).
__device__ void scan_gcount_512(const int* gcount, int NBUK, int* p, int* gb_ex) {
    int t = threadIdx.x;
    int v = (t < 256) ? ((t < NBUK) ? gcount[t] : 0) : 0;
    if (t < 256) p[t] = v;
    __syncthreads();
    for (int st = 1; st < 256; st <<= 1) {
        int add = (t >= st && t < 256) ? p[t - st] : 0;
        __syncthreads();
        if (t < 256) p[t] += add;
        __syncthreads();
    }
    if (t < 256) gb_ex[t] = p[t] - v;
    __syncthreads();
}

// P3: block-local counting sort by bucket; write packed (r | clocal<<23)
// to bucket-major staging (4B/edge). Zero global atomics.
__global__ void __launch_bounds__(256) k_p3(
        const void* __restrict__ ei, long long E, int n, int NBUK, int NBLK,
        const int* __restrict__ bhist, const int* __restrict__ gcount,
        unsigned* __restrict__ gstag, const int* __restrict__ flags) {
    __shared__ int hist[256], lbase[256], rsv[256], lcur[256], s[256], gb[256];
    __shared__ unsigned stage[CH];
    int t = threadIdx.x;
    int blk = blockIdx.x;
    scan_gcount(gcount, NBUK, s, gb);
    long long base = (long long)blk * CH;
    int cnt = (int)min((long long)CH, E - base);
    int me = flags[FLAG_ME];
    hist[t] = 0;
    __syncthreads();
    for (int i = t; i < cnt; i += 256) {
        int c = idx_at(ei, E + base + i, me);
        atomicAdd(&hist[min(c >> SH, NBUK - 1)], 1);
    }
    __syncthreads();
    int v = hist[t];
    s[t] = v;
    __syncthreads();
    for (int st = 1; st < 256; st <<= 1) {
        int add = (t >= st) ? s[t - st] : 0;
        __syncthreads();
        s[t] += add;
        __syncthreads();
    }
    lbase[t] = s[t] - v;
    lcur[t] = s[t] - v;
    if (t < NBUK) rsv[t] = gb[t] + bhist[(size_t)t * NBLK + blk];
    __syncthreads();
    for (int i = t; i < cnt; i += 256) {
        long long e = base + i;
        int r = idx_at(ei, e, me);
        int c = idx_at(ei, E + e, me);
        int b = min(c >> SH, NBUK - 1);
        unsigned pkv = ((unsigned)r & RMASK) |
                       (((unsigned)(c - (b << SH)) & (WC - 1)) << 23);
        int slot = atomicAdd(&lcur[b], 1);
        stage[slot] = pkv;
    }
    __syncthreads();
    // slot i belongs to bucket b where lbase[b] <= i < lbase[b]+hist[b]
    for (int i = t; i < cnt; i += 256) {
        unsigned pkv = stage[i];
        int lo = 0, hi = NBUK - 1;
        while (lo < hi) {
            int mid = (lo + hi + 1) >> 1;
            if (lbase[mid] <= i) lo = mid; else hi = mid - 1;
        }
        gstag[rsv[lo] + (i - lbase[lo])] = pkv;
    }
}

// P4 (512 threads, r18 version): one block per bucket: col histogram + scan
// -> off/dinv; rowidx placement into the bucket's contiguous slice.
__global__ void __launch_bounds__(512) k_p4(
        const unsigned* __restrict__ gstag, const int* __restrict__ gcount,
        int* __restrict__ off, float* __restrict__ dinv,
        int* __restrict__ rowidx, int n, int NBUK) {
    __shared__ int hist[WC], lofs[WC], cur[WC], p[512], gb[256];
    int t = threadIdx.x;  // 0..511
    int b = blockIdx.x;
    int cbase = b << SH;
    scan_gcount_512(gcount, NBUK, p, gb);
    int e0 = gb[b];
    int e1 = e0 + gcount[b];
    int cnt = e1 - e0;
    if (b == NBUK - 1 && t == 0) off[n] = e1;  // == E
    hist[t] = 0;
    __syncthreads();
    for (int i = t; i < cnt; i += 512) {
        atomicAdd(&hist[gstag[e0 + i] >> 23], 1);
    }
    __syncthreads();
    // 512-wide exclusive scan, 1 elem/thread
    int v = hist[t];
    p[t] = v;
    __syncthreads();
    for (int st = 1; st < 512; st <<= 1) {
        int add = (t >= st) ? p[t - st] : 0;
        __syncthreads();
        p[t] += add;
        __syncthreads();
    }
    int excl = p[t] - v;
    lofs[t] = excl;
    cur[t] = excl;
    __syncthreads();
    int ncols = n - cbase;
    if (ncols < 0) ncols = 0;
    if (ncols > WC) ncols = WC;
    if (t < ncols) {
        off[cbase + t] = e0 + lofs[t];
        dinv[cbase + t] = rsqrtf((float)(hist[t] + 1));  // +1 self-loop
    }
    for (int i = t; i < cnt; i += 512) {
        unsigned pkv = gstag[e0 + i];
        int cl = (int)(pkv >> 23);
        int slot = atomicAdd(&cur[cl], 1);
        rowidx[e0 + slot] = (int)(pkv & RMASK);
    }
}

// z0: z[node] = emb[xidx[node]] * dinv[node], bf16 out; thread = 16B chunk.
__global__ void __launch_bounds__(256) k_z0(
        const void* __restrict__ xidx, const float4* __restrict__ emb4,
        const float* __restrict__ dinv, uint4* __restrict__ z, int n,
        const int* __restrict__ flags) {
    int i = blockIdx.x * 256 + threadIdx.x;
    if (i >= n * 8) return;
    int node = i >> 3, q = i & 7;
    int xi = idx_at(xidx, node, flags[FLAG_MX]);
    if ((unsigned)xi >= (unsigned)n) xi = 0;
    float d = dinv[node];
    float4 a = emb4[(long long)xi * 16 + q * 2];
    float4 b = emb4[(long long)xi * 16 + q * 2 + 1];
    uint4 o;
    o.x = pk(a.x * d, a.y * d);
    o.y = pk(a.z * d, a.w * d);
    o.z = pk(b.x * d, b.y * d);
    o.w = pk(b.z * d, b.w * d);
    z[(long long)node * 8 + q] = o;
}

__device__ inline void acc8(float* acc, uint4 s) {
    acc[0] += bflo(s.x); acc[1] += bfhi(s.x);
    acc[2] += bflo(s.y); acc[3] += bfhi(s.y);
    acc[4] += bflo(s.z); acc[5] += bfhi(s.z);
    acc[6] += bflo(s.w); acc[7] += bfhi(s.w);
}

// Half-edge-list hop body: this thread (node, half h, chunk q) accumulates
// zin rows of its half [lo,hi). h==0 also folds the self-loop. Plain loads,
// unroll-4 (r13-proven core). Caller combines halves via shfl_xor(8).
__device__ inline void hop_half(
        float* acc, const uint4* __restrict__ zin,
        const int* __restrict__ rowidx, int node, int h, int q,
        const int* __restrict__ off) {
    if (h == 0) {
        uint4 s = zin[(long long)node * 8 + q];  // self-loop
        acc[0] = bflo(s.x); acc[1] = bfhi(s.x);
        acc[2] = bflo(s.y); acc[3] = bfhi(s.y);
        acc[4] = bflo(s.z); acc[5] = bfhi(s.z);
        acc[6] = bflo(s.w); acc[7] = bfhi(s.w);
    } else {
#pragma unroll 8
        for (int i = 0; i < 8; i++) acc[i] = 0.f;
    }
    int e0 = off[node], e1 = off[node + 1];
    int half = (e1 - e0 + 1) >> 1;
    int lo = e0 + h * half;
    int hi = h ? e1 : (e0 + half);
    int e = lo;
    for (; e + 4 <= hi; e += 4) {
        int r0 = rowidx[e + 0];
        int r1 = rowidx[e + 1];
        int r2 = rowidx[e + 2];
        int r3 = rowidx[e + 3];
        uint4 s0 = zin[(long long)r0 * 8 + q];
        uint4 s1 = zin[(long long)r1 * 8 + q];
        uint4 s2 = zin[(long long)r2 * 8 + q];
        uint4 s3 = zin[(long long)r3 * 8 + q];
        acc8(acc, s0);
        acc8(acc, s1);
        acc8(acc, s2);
        acc8(acc, s3);
    }
    for (; e < hi; e++) {
        int r = rowidx[e];
        acc8(acc, zin[(long long)r * 8 + q]);
    }
}

// hop: 16 lanes per node (2 half-lists x 8 chunks); combine via shfl_xor(8).
// Mid hops only (scale d*d). 4 nodes per wave.
__global__ void __launch_bounds__(256) k_hop(
        const uint4* __restrict__ zin, uint4* __restrict__ zout,
        const float* __restrict__ dinv, const int* __restrict__ off,
        const int* __restrict__ rowidx, int n) {
    int tid = blockIdx.x * 256 + threadIdx.x;
    int node = tid >> 4;
    if (node >= n) return;
    int h = (tid >> 3) & 1;
    int q = tid & 7;
    float acc[8];
    hop_half(acc, zin, rowidx, node, h, q, off);
#pragma unroll 8
    for (int i = 0; i < 8; i++) acc[i] += __shfl_xor(acc[i], 8);
    if (h == 0) {
        float d = dinv[node];
        float sc = d * d;
        uint4 o;
        o.x = pk(acc[0] * sc, acc[1] * sc);
        o.y = pk(acc[2] * sc, acc[3] * sc);
        o.z = pk(acc[4] * sc, acc[5] * sc);
        o.w = pk(acc[6] * sc, acc[7] * sc);
        zout[(long long)node * 8 + q] = o;
    }
}

// Fused hop3 (scale d, last hop) + MFMA linear. One block = 16 nodes.
// Phase A: 16-lane/node hop, pack z3 -> swizzled 2KB LDS tile.
// Phase B: 4 waves x (16-node M-tile x one 16-col N-tile) MFMA from LDS
// A-fragments + precomputed bf16 W (w8).
__global__ void __launch_bounds__(256) k_hop3_lin(
        const uint4* __restrict__ zin, const float* __restrict__ dinv,
        const int* __restrict__ off, const int* __restrict__ rowidx,
        const unsigned short* __restrict__ w8, const float* __restrict__ bias,
        float* __restrict__ out, int n) {
    __shared__ uint4 z3[16][8];  // [local node][16B chunk], chunk XOR-swizzled
    int t = threadIdx.x;
    int l = t >> 4;                      // local node 0..15
    int h = (t >> 3) & 1;                // half-list 0..1
    int q = t & 7;                       // 16B chunk 0..7
    int node = blockIdx.x * 16 + l;
    float acc[8];
    if (node < n) {
        hop_half(acc, zin, rowidx, node, h, q, off);
    } else {
#pragma unroll 8
        for (int i = 0; i < 8; i++) acc[i] = 0.f;
    }
#pragma unroll 8
    for (int i = 0; i < 8; i++) acc[i] += __shfl_xor(acc[i], 8);
    if (h == 0) {
        uint4 o = {0u, 0u, 0u, 0u};      // pad nodes contribute zeros to MFMA
        if (node < n) {
            float d = dinv[node];        // last hop: single dinv
            o.x = pk(acc[0] * d, acc[1] * d);
            o.y = pk(acc[2] * d, acc[3] * d);
            o.z = pk(acc[4] * d, acc[5] * d);
            o.w = pk(acc[6] * d, acc[7] * d);
        }
        z3[l][q ^ (l & 7)] = o;  // swizzle: breaks the 128B-stride bank conflict
    }
    __syncthreads();

    // Phase B: 4 waves; wave wv owns N-tile wv (16 output cols).
    int lane = t & 63, wv = t >> 6;
    int col = lane & 15, quad = lane >> 4;
    int node0 = blockIdx.x * 16;
    int ln = col;                        // local node for A fragment
    short8 a[2];
#pragma unroll
    for (int s = 0; s < 2; s++) {
        int c = s * 4 + quad;
        a[s] = *(const short8*)&z3[ln][c ^ (ln & 7)];
    }
    const short8* wp = (const short8*)w8;  // [64 rows][8 chunks of 8 bf16]
    float bv = bias[wv * 16 + col];
    f32x4 acc4 = {bv, bv, bv, bv};
    acc4 = __builtin_amdgcn_mfma_f32_16x16x32_bf16(
        a[0], wp[(wv * 16 + col) * 8 + 0 * 4 + quad], acc4, 0, 0, 0);
    acc4 = __builtin_amdgcn_mfma_f32_16x16x32_bf16(
        a[1], wp[(wv * 16 + col) * 8 + 1 * 4 + quad], acc4, 0, 0, 0);
#pragma unroll
    for (int r = 0; r < 4; r++) {
        int nd = node0 + quad * 4 + r;
        if (nd < n) out[(size_t)nd * 64 + wv * 16 + col] = acc4[r];
    }
}

extern "C" void kernel_launch(void* const* d_in, const int* in_sizes, int n_in,
                              void* d_out, int out_size, void* d_ws, size_t ws_size,
                              hipStream_t stream) {
    const void* xidx = d_in[0];
    const void* ei = d_in[1];
    const float* emb = (const float*)d_in[2];
    const float* w = (const float*)d_in[3];
    const float* b = (const float*)d_in[4];

    const int n = in_sizes[0];
    const long long E = in_sizes[1] / 2;
    int NBUK = (int)((n + WC - 1) >> SH);
    if (NBUK > 256) NBUK = 256;  // dataset: n=100k -> 196
    const int NBLK = (int)((E + CH - 1) / CH);

    char* p = (char*)d_ws;
    auto alloc = [&](size_t bytes) -> void* {
        void* r = (void*)p;
        p += (bytes + 255) & ~(size_t)255;
        return r;
    };
    int* flags = (int*)alloc(256);
    float* dinv = (float*)alloc((size_t)n * 4);
    int* off = (int*)alloc((size_t)(n + 1) * 4);
    int* gcount = (int*)alloc(257 * 4);
    int* bhist = (int*)alloc((size_t)NBLK * NBUK * 4);
    int* rowidx = (int*)alloc((size_t)E * 4);
    uint4* zA = (uint4*)alloc((size_t)n * 64 * 2);       // bf16 z (12.8 MB)
    unsigned short* w8 = (unsigned short*)alloc(4096 * 2);  // bf16 W
    uint4* zS = (uint4*)d_out;                           // bf16 z in d_out 1st half

    // packed staging (4B/edge) in d_out's 2nd half (E*4 <= n*64*2 here)
    unsigned* gstag;
    if ((size_t)E * 4 <= (size_t)n * 64 * 2)
        gstag = (unsigned*)((char*)d_out + (size_t)n * 64 * 2);
    else
        gstag = (unsigned*)alloc((size_t)E * 4);

    k_p1<<<NBLK, 256, 0, stream>>>(ei, xidx, E, n, NBUK, NBLK, bhist, flags);
    k_p2a<<<NBUK + 1, 256, 0, stream>>>(bhist, gcount, NBLK, NBUK, w, w8);
    k_p3<<<NBLK, 256, 0, stream>>>(ei, E, n, NBUK, NBLK, bhist, gcount, gstag, flags);
    k_p4<<<NBUK, 512, 0, stream>>>(gstag, gcount, off, dinv, rowidx, n, NBUK);

    const int gF = (n * 8 + 255) / 256;    // z0: 8 threads/node
    const int gH = (n * 16 + 255) / 256;   // hops: 16 threads/node
    const int gL = (n + 15) / 16;          // fused hop3+lin: 16 nodes/block

    // z0 -> zA(ws); hop1 zA->zS(d_out); hop2 zS->zA; fused hop3+lin zA -> d_out.
    // (fused kernel writes d_out; its gather input zA is workspace -> no race)
    k_z0<<<gF, 256, 0, stream>>>(xidx, (const float4*)emb, dinv, zA, n, flags);
    k_hop<<<gH, 256, 0, stream>>>(zA, zS, dinv, off, rowidx, n);
    k_hop<<<gH, 256, 0, stream>>>(zS, zA, dinv, off, rowidx, n);
    k_hop3_lin<<<gL, 256, 0, stream>>>(zA, dinv, off, rowidx, w8, b,
                                       (float*)d_out, n);
}

// Round 8
// 244.435 us; speedup vs baseline: 1.8946x; 1.0414x over previous
//
#include <hip/hip_runtime.h>
#include <hip/hip_bf16.h>
#include <math.h>

// SGConv: x = emb[x_indices]; 3 hops of D^-1/2 (A+I) D^-1/2; out = x3 @ W^T + b.
// z-space: z = dinv*x; hop: z' = dinv^2*(z[c] + sum_{r->c} z[r]); last hop dinv^1.
// LEDGER (verified r0-18): emb/w/b fp32, out fp32, ei contiguous (2,E),
// index widths runtime-classified, bf16 z validated (absmax 4.9e-4).
// r18 = 250.5us (best): W-precompute in p2a extra block + fused hop3+linear.
// r19 FAILED (463us): p4 insertion sort O(k^2); nt LOADS on rowidx (latency-
// critical) ~900cy misses. r20 FAILED (299us): source-sliced hops — blocks
// not pass-synchronized, L2 working set stays all of z; FETCH 68.5MB.
// r21 NEUTRAL (254.6us): 16 lanes/node (2x waves, 0.5x work/thread) — total
// MLP unchanged; hops not MLP-bound. Conclusion: gather stream is bound by
// L2 capacity contention / L3 random 128B throughput (~4.5 TB/s effective).
// r22 (this round): exact r18 structure + ONE variable: NONTEMPORAL STORES
// on zout (hops) and out (fused lin). zin lines are re-gathered ~16x/hop;
// zout write-allocate (12.8MB, zero reuse) evicts them from the 4MB/XCD L2.
// nt store = write no-allocate -> protects the gather set. (r19's nt
// mistake was on LOADS; stores are fire-and-forget.)

#define FLAG_MX 0
#define FLAG_ME 1
#define SH 9        // 512 cols per bucket
#define WC 512      // cols per bucket
#define CH 4096     // edges per P1/P3 block
#define RMASK 0x7FFFFFu

using short8 = __attribute__((ext_vector_type(8))) short;
using f32x4 = __attribute__((ext_vector_type(4))) float;
using uint32x4 = __attribute__((ext_vector_type(4))) unsigned;

__device__ inline int idx_at(const void* p, long long i, int mode) {
    switch (mode) {
        case 1: return (int)((const long long*)p)[i];
        case 2: return (int)((const float*)p)[i];
        case 3: return (int)((const double*)p)[i];
        default: return ((const int*)p)[i];
    }
}

// bf16 helpers (RNE pack, shift unpack)
__device__ inline unsigned short f2bf(float f) {
    union { float f; unsigned u; } v; v.f = f;
    unsigned r = v.u + 0x7FFFu + ((v.u >> 16) & 1u);
    return (unsigned short)(r >> 16);
}
__device__ inline float bflo(unsigned d) { union { unsigned u; float f; } v; v.u = d << 16; return v.f; }
__device__ inline float bfhi(unsigned d) { union { unsigned u; float f; } v; v.u = d & 0xFFFF0000u; return v.f; }
__device__ inline unsigned pk(float a, float b) {
    return (unsigned)f2bf(a) | ((unsigned)f2bf(b) << 16);
}

__device__ int detect_me_block(const void* ei, int n, int* sbuf) {
    int t = threadIdx.x;
    int oke = 15;
    const int* w = (const int*)ei;
    const long long* L = (const long long*)ei;
    const float* f = (const float*)ei;
    const double* d = (const double*)ei;
    for (int k = t; k < 2048; k += 256) {
        if (!((unsigned)w[k] < (unsigned)n)) oke &= ~1;
        long long lv = L[k];
        if (!(lv >= 0 && lv < (long long)n)) oke &= ~2;
        float fv = f[k];
        if (!(fv >= 0.f && fv < (float)n && fv == truncf(fv))) oke &= ~4;
        double dv = d[k];
        if (!(dv >= 0.0 && dv < (double)n && dv == trunc(dv))) oke &= ~8;
    }
    sbuf[t] = oke;
    __syncthreads();
    for (int st = 128; st; st >>= 1) {
        if (t < st) sbuf[t] &= sbuf[t + st];
        __syncthreads();
    }
    int r = sbuf[0];
    __syncthreads();
    return (r & 2) ? 1 : (r & 8) ? 3 : (r & 4) ? 2 : 0;
}

__device__ int detect_mx_block(const void* xidx, int* sbuf) {
    int t = threadIdx.x;
    int okx = 15;
    const int* w = (const int*)xidx;
    const long long* L = (const long long*)xidx;
    const float* f = (const float*)xidx;
    const double* d = (const double*)xidx;
    for (int k = t; k < 2048; k += 256) {
        if (w[k] != k) okx &= ~1;
        if (L[k] != (long long)k) okx &= ~2;
        if (!(f[k] == (float)k)) okx &= ~4;
        if (!(d[k] == (double)k)) okx &= ~8;
    }
    sbuf[t] = okx;
    __syncthreads();
    for (int st = 128; st; st >>= 1) {
        if (t < st) sbuf[t] &= sbuf[t + st];
        __syncthreads();
    }
    int r = sbuf[0];
    __syncthreads();
    return (r & 2) ? 1 : (r & 8) ? 3 : (r & 4) ? 2 : 0;
}

// P1: inline classify (block 0 publishes flags) + per-block bucket histogram
// -> bhist[b*NBLK + blk] (bucket-major).
__global__ void __launch_bounds__(256) k_p1(
        const void* __restrict__ ei, const void* __restrict__ xidx,
        long long E, int n, int NBUK, int NBLK,
        int* __restrict__ bhist, int* __restrict__ flags) {
    __shared__ int hist[256];
    __shared__ int sbuf[256];
    int t = threadIdx.x;
    int blk = blockIdx.x;
    int me = detect_me_block(ei, n, sbuf);
    if (blk == 0) {
        int mx = detect_mx_block(xidx, sbuf);
        if (t == 0) { flags[FLAG_ME] = me; flags[FLAG_MX] = mx; }
    }
    long long base = (long long)blk * CH;
    int cnt = (int)min((long long)CH, E - base);
    hist[t] = 0;
    __syncthreads();
    for (int i = t; i < cnt; i += 256) {
        int c = idx_at(ei, E + base + i, me);
        int b = min(c >> SH, NBUK - 1);
        atomicAdd(&hist[b], 1);
    }
    __syncthreads();
    if (t < NBUK) bhist[(size_t)t * NBLK + blk] = hist[t];
}

// P2a: per-bucket chunked LDS exclusive scan over block-counts (in place);
// gcount[b] = bucket total. Extra block (b == NBUK) converts W -> bf16 once.
__global__ void __launch_bounds__(256) k_p2a(
        int* __restrict__ bhist, int* __restrict__ gcount, int NBLK, int NBUK,
        const float* __restrict__ w, unsigned short* __restrict__ w8) {
    __shared__ int s[256];
    int b = blockIdx.x;
    int t = threadIdx.x;
    if (b >= NBUK) {  // W precompute: 64x64 fp32 -> bf16 (row-major [o][k])
        for (int i = t; i < 4096; i += 256) w8[i] = f2bf(w[i]);
        return;
    }
    int* row = bhist + (size_t)b * NBLK;
    int carry = 0;
    for (int base = 0; base < NBLK; base += 256) {
        int i = base + t;
        int v = (i < NBLK) ? row[i] : 0;
        s[t] = v;
        __syncthreads();
        for (int st = 1; st < 256; st <<= 1) {
            int add = (t >= st) ? s[t - st] : 0;
            __syncthreads();
            s[t] += add;
            __syncthreads();
        }
        if (i < NBLK) row[i] = carry + s[t] - v;  // exclusive
        int total = s[255];
        __syncthreads();
        carry += total;
    }
    if (t == 0) gcount[b] = carry;
}

// in-block exclusive scan of gcount (NBUK <= 256), 256-thread version.
__device__ void scan_gcount(const int* gcount, int NBUK, int* p, int* gb_ex) {
    int t = threadIdx.x;
    int v = (t < NBUK) ? gcount[t] : 0;
    p[t] = v;
    __syncthreads();
    for (int st = 1; st < 256; st <<= 1) {
        int add = (t >= st) ? p[t - st] : 0;
        __syncthreads();
        p[t] += add;
        __syncthreads();
    }
    gb_ex[t] = p[t] - v;
    __syncthreads();
}

// 512-thread version (threads >= 256 ride along through the syncs).
__device__ void scan_gcount_512(const int* gcount, int NBUK, int* p, int* gb_ex) {
    int t = threadIdx.x;
    int v = (t < 256) ? ((t < NBUK) ? gcount[t] : 0) : 0;
    if (t < 256) p[t] = v;
    __syncthreads();
    for (int st = 1; st < 256; st <<= 1) {
        int add = (t >= st && t < 256) ? p[t - st] : 0;
        __syncthreads();
        if (t < 256) p[t] += add;
        __syncthreads();
    }
    if (t < 256) gb_ex[t] = p[t] - v;
    __syncthreads();
}

// P3: block-local counting sort by bucket; write packed (r | clocal<<23)
// to bucket-major staging (4B/edge). Zero global atomics.
__global__ void __launch_bounds__(256) k_p3(
        const void* __restrict__ ei, long long E, int n, int NBUK, int NBLK,
        const int* __restrict__ bhist, const int* __restrict__ gcount,
        unsigned* __restrict__ gstag, const int* __restrict__ flags) {
    __shared__ int hist[256], lbase[256], rsv[256], lcur[256], s[256], gb[256];
    __shared__ unsigned stage[CH];
    int t = threadIdx.x;
    int blk = blockIdx.x;
    scan_gcount(gcount, NBUK, s, gb);
    long long base = (long long)blk * CH;
    int cnt = (int)min((long long)CH, E - base);
    int me = flags[FLAG_ME];
    hist[t] = 0;
    __syncthreads();
    for (int i = t; i < cnt; i += 256) {
        int c = idx_at(ei, E + base + i, me);
        atomicAdd(&hist[min(c >> SH, NBUK - 1)], 1);
    }
    __syncthreads();
    int v = hist[t];
    s[t] = v;
    __syncthreads();
    for (int st = 1; st < 256; st <<= 1) {
        int add = (t >= st) ? s[t - st] : 0;
        __syncthreads();
        s[t] += add;
        __syncthreads();
    }
    lbase[t] = s[t] - v;
    lcur[t] = s[t] - v;
    if (t < NBUK) rsv[t] = gb[t] + bhist[(size_t)t * NBLK + blk];
    __syncthreads();
    for (int i = t; i < cnt; i += 256) {
        long long e = base + i;
        int r = idx_at(ei, e, me);
        int c = idx_at(ei, E + e, me);
        int b = min(c >> SH, NBUK - 1);
        unsigned pkv = ((unsigned)r & RMASK) |
                       (((unsigned)(c - (b << SH)) & (WC - 1)) << 23);
        int slot = atomicAdd(&lcur[b], 1);
        stage[slot] = pkv;
    }
    __syncthreads();
    // slot i belongs to bucket b where lbase[b] <= i < lbase[b]+hist[b]
    for (int i = t; i < cnt; i += 256) {
        unsigned pkv = stage[i];
        int lo = 0, hi = NBUK - 1;
        while (lo < hi) {
            int mid = (lo + hi + 1) >> 1;
            if (lbase[mid] <= i) lo = mid; else hi = mid - 1;
        }
        gstag[rsv[lo] + (i - lbase[lo])] = pkv;
    }
}

// P4 (512 threads): one block per bucket: col histogram + scan -> off/dinv;
// rowidx placement into the bucket's contiguous slice.
__global__ void __launch_bounds__(512) k_p4(
        const unsigned* __restrict__ gstag, const int* __restrict__ gcount,
        int* __restrict__ off, float* __restrict__ dinv,
        int* __restrict__ rowidx, int n, int NBUK) {
    __shared__ int hist[WC], lofs[WC], cur[WC], p[512], gb[256];
    int t = threadIdx.x;  // 0..511
    int b = blockIdx.x;
    int cbase = b << SH;
    scan_gcount_512(gcount, NBUK, p, gb);
    int e0 = gb[b];
    int e1 = e0 + gcount[b];
    int cnt = e1 - e0;
    if (b == NBUK - 1 && t == 0) off[n] = e1;  // == E
    hist[t] = 0;
    __syncthreads();
    for (int i = t; i < cnt; i += 512) {
        atomicAdd(&hist[gstag[e0 + i] >> 23], 1);
    }
    __syncthreads();
    // 512-wide exclusive scan, 1 elem/thread
    int v = hist[t];
    p[t] = v;
    __syncthreads();
    for (int st = 1; st < 512; st <<= 1) {
        int add = (t >= st) ? p[t - st] : 0;
        __syncthreads();
        p[t] += add;
        __syncthreads();
    }
    int excl = p[t] - v;
    lofs[t] = excl;
    cur[t] = excl;
    __syncthreads();
    int ncols = n - cbase;
    if (ncols < 0) ncols = 0;
    if (ncols > WC) ncols = WC;
    if (t < ncols) {
        off[cbase + t] = e0 + lofs[t];
        dinv[cbase + t] = rsqrtf((float)(hist[t] + 1));  // +1 self-loop
    }
    for (int i = t; i < cnt; i += 512) {
        unsigned pkv = gstag[e0 + i];
        int cl = (int)(pkv >> 23);
        int slot = atomicAdd(&cur[cl], 1);
        rowidx[e0 + slot] = (int)(pkv & RMASK);
    }
}

// z0: z[node] = emb[xidx[node]] * dinv[node], bf16 out; thread = 16B chunk.
// Plain store (leftover warm set helps hop1's gathers).
__global__ void __launch_bounds__(256) k_z0(
        const void* __restrict__ xidx, const float4* __restrict__ emb4,
        const float* __restrict__ dinv, uint4* __restrict__ z, int n,
        const int* __restrict__ flags) {
    int i = blockIdx.x * 256 + threadIdx.x;
    if (i >= n * 8) return;
    int node = i >> 3, q = i & 7;
    int xi = idx_at(xidx, node, flags[FLAG_MX]);
    if ((unsigned)xi >= (unsigned)n) xi = 0;
    float d = dinv[node];
    float4 a = emb4[(long long)xi * 16 + q * 2];
    float4 b = emb4[(long long)xi * 16 + q * 2 + 1];
    uint4 o;
    o.x = pk(a.x * d, a.y * d);
    o.y = pk(a.z * d, a.w * d);
    o.z = pk(b.x * d, b.y * d);
    o.w = pk(b.z * d, b.w * d);
    z[(long long)node * 8 + q] = o;
}

__device__ inline void acc8(float* acc, uint4 s) {
    acc[0] += bflo(s.x); acc[1] += bfhi(s.x);
    acc[2] += bflo(s.y); acc[3] += bfhi(s.y);
    acc[4] += bflo(s.z); acc[5] += bfhi(s.z);
    acc[6] += bflo(s.w); acc[7] += bfhi(s.w);
}

// hop: 8 contiguous nodes per wave; lane = one 16B chunk (8 bf16).
// Inner loop unrolled x4 (r13-proven structure). Mid hops only (scale d*d).
// zout store NONTEMPORAL: write no-allocate protects the 16x-reused zin
// gather set in the 4MB/XCD L2 (r22 single variable).
__global__ void __launch_bounds__(256) k_hop(
        const uint4* __restrict__ zin, uint4* __restrict__ zout,
        const float* __restrict__ dinv, const int* __restrict__ off,
        const int* __restrict__ rowidx, int n) {
    int tid = blockIdx.x * 256 + threadIdx.x;
    int node = tid >> 3;
    int q = tid & 7;
    if (node >= n) return;
    float acc[8];
    {
        uint4 s = zin[(long long)node * 8 + q];  // self-loop
        acc[0] = bflo(s.x); acc[1] = bfhi(s.x);
        acc[2] = bflo(s.y); acc[3] = bfhi(s.y);
        acc[4] = bflo(s.z); acc[5] = bfhi(s.z);
        acc[6] = bflo(s.w); acc[7] = bfhi(s.w);
    }
    int e0 = off[node], e1 = off[node + 1];
    int e = e0;
    for (; e + 4 <= e1; e += 4) {
        int r0 = rowidx[e + 0];
        int r1 = rowidx[e + 1];
        int r2 = rowidx[e + 2];
        int r3 = rowidx[e + 3];
        uint4 s0 = zin[(long long)r0 * 8 + q];
        uint4 s1 = zin[(long long)r1 * 8 + q];
        uint4 s2 = zin[(long long)r2 * 8 + q];
        uint4 s3 = zin[(long long)r3 * 8 + q];
        acc8(acc, s0);
        acc8(acc, s1);
        acc8(acc, s2);
        acc8(acc, s3);
    }
    for (; e < e1; e++) {
        int r = rowidx[e];
        acc8(acc, zin[(long long)r * 8 + q]);
    }
    float d = dinv[node];
    float sc = d * d;
    uint32x4 o;
    o[0] = pk(acc[0] * sc, acc[1] * sc);
    o[1] = pk(acc[2] * sc, acc[3] * sc);
    o[2] = pk(acc[4] * sc, acc[5] * sc);
    o[3] = pk(acc[6] * sc, acc[7] * sc);
    __builtin_nontemporal_store(o, (uint32x4*)&zout[(long long)node * 8 + q]);
}

// Fused hop3 (scale d, last hop) + MFMA linear. One block = 32 nodes.
// Phase A: r13 hop loop, pack z3 -> swizzled 4KB LDS tile.
// Phase B: 4 waves x (1 M-tile of 16 nodes, 2 N-tiles of 16 cols) MFMA
// from LDS A-fragments + precomputed bf16 W (w8). out stores nontemporal
// (final output, never re-read; protects zin gather set).
__global__ void __launch_bounds__(256) k_hop3_lin(
        const uint4* __restrict__ zin, const float* __restrict__ dinv,
        const int* __restrict__ off, const int* __restrict__ rowidx,
        const unsigned short* __restrict__ w8, const float* __restrict__ bias,
        float* __restrict__ out, int n) {
    __shared__ uint4 z3[32][8];  // [local node][16B chunk], chunk XOR-swizzled
    int t = threadIdx.x;
    int l = t >> 3;                      // local node 0..31
    int q = t & 7;                       // 16B chunk 0..7
    int node = blockIdx.x * 32 + l;
    uint4 o = {0u, 0u, 0u, 0u};          // pad nodes contribute zeros to MFMA
    if (node < n) {
        float acc[8];
        {
            uint4 s = zin[(long long)node * 8 + q];  // self-loop
            acc[0] = bflo(s.x); acc[1] = bfhi(s.x);
            acc[2] = bflo(s.y); acc[3] = bfhi(s.y);
            acc[4] = bflo(s.z); acc[5] = bfhi(s.z);
            acc[6] = bflo(s.w); acc[7] = bfhi(s.w);
        }
        int e0 = off[node], e1 = off[node + 1];
        int e = e0;
        for (; e + 4 <= e1; e += 4) {
            int r0 = rowidx[e + 0];
            int r1 = rowidx[e + 1];
            int r2 = rowidx[e + 2];
            int r3 = rowidx[e + 3];
            uint4 s0 = zin[(long long)r0 * 8 + q];
            uint4 s1 = zin[(long long)r1 * 8 + q];
            uint4 s2 = zin[(long long)r2 * 8 + q];
            uint4 s3 = zin[(long long)r3 * 8 + q];
            acc8(acc, s0);
            acc8(acc, s1);
            acc8(acc, s2);
            acc8(acc, s3);
        }
        for (; e < e1; e++) {
            int r = rowidx[e];
            acc8(acc, zin[(long long)r * 8 + q]);
        }
        float d = dinv[node];  // last hop: single dinv
        o.x = pk(acc[0] * d, acc[1] * d);
        o.y = pk(acc[2] * d, acc[3] * d);
        o.z = pk(acc[4] * d, acc[5] * d);
        o.w = pk(acc[6] * d, acc[7] * d);
    }
    z3[l][q ^ (l & 7)] = o;  // swizzle: breaks the 128B-stride bank conflict
    __syncthreads();

    // Phase B: lane/wave decomposition identical to r18 k_lin_mfma layout.
    int lane = t & 63, wv = t >> 6;
    int tile = wv >> 1;                  // 0..1: M-tile within block
    int nh = wv & 1;                     // 0..1: which pair of N-tiles
    int col = lane & 15, quad = lane >> 4;
    int node0 = blockIdx.x * 32 + tile * 16;
    int ln = tile * 16 + col;            // local node for A fragment
    short8 a[2];
#pragma unroll
    for (int s = 0; s < 2; s++) {
        int c = s * 4 + quad;
        a[s] = *(const short8*)&z3[ln][c ^ (ln & 7)];
    }
    const short8* wp = (const short8*)w8;  // [64 rows][8 chunks of 8 bf16]
#pragma unroll
    for (int j = 0; j < 2; j++) {
        int tN = nh * 2 + j;
        float bv = bias[tN * 16 + col];
        f32x4 acc4 = {bv, bv, bv, bv};
        acc4 = __builtin_amdgcn_mfma_f32_16x16x32_bf16(
            a[0], wp[(tN * 16 + col) * 8 + 0 * 4 + quad], acc4, 0, 0, 0);
        acc4 = __builtin_amdgcn_mfma_f32_16x16x32_bf16(
            a[1], wp[(tN * 16 + col) * 8 + 1 * 4 + quad], acc4, 0, 0, 0);
#pragma unroll
        for (int r = 0; r < 4; r++) {
            int nd = node0 + quad * 4 + r;
            if (nd < n)
                __builtin_nontemporal_store(
                    acc4[r], &out[(size_t)nd * 64 + tN * 16 + col]);
        }
    }
}

extern "C" void kernel_launch(void* const* d_in, const int* in_sizes, int n_in,
                              void* d_out, int out_size, void* d_ws, size_t ws_size,
                              hipStream_t stream) {
    const void* xidx = d_in[0];
    const void* ei = d_in[1];
    const float* emb = (const float*)d_in[2];
    const float* w = (const float*)d_in[3];
    const float* b = (const float*)d_in[4];

    const int n = in_sizes[0];
    const long long E = in_sizes[1] / 2;
    int NBUK = (int)((n + WC - 1) >> SH);
    if (NBUK > 256) NBUK = 256;  // dataset: n=100k -> 196
    const int NBLK = (int)((E + CH - 1) / CH);

    char* p = (char*)d_ws;
    auto alloc = [&](size_t bytes) -> void* {
        void* r = (void*)p;
        p += (bytes + 255) & ~(size_t)255;
        return r;
    };
    int* flags = (int*)alloc(256);
    float* dinv = (float*)alloc((size_t)n * 4);
    int* off = (int*)alloc((size_t)(n + 1) * 4);
    int* gcount = (int*)alloc(257 * 4);
    int* bhist = (int*)alloc((size_t)NBLK * NBUK * 4);
    int* rowidx = (int*)alloc((size_t)E * 4);
    uint4* zA = (uint4*)alloc((size_t)n * 64 * 2);       // bf16 z (12.8 MB)
    unsigned short* w8 = (unsigned short*)alloc(4096 * 2);  // bf16 W
    uint4* zS = (uint4*)d_out;                           // bf16 z in d_out 1st half

    // packed staging (4B/edge) in d_out's 2nd half (E*4 <= n*64*2 here)
    unsigned* gstag;
    if ((size_t)E * 4 <= (size_t)n * 64 * 2)
        gstag = (unsigned*)((char*)d_out + (size_t)n * 64 * 2);
    else
        gstag = (unsigned*)alloc((size_t)E * 4);

    k_p1<<<NBLK, 256, 0, stream>>>(ei, xidx, E, n, NBUK, NBLK, bhist, flags);
    k_p2a<<<NBUK + 1, 256, 0, stream>>>(bhist, gcount, NBLK, NBUK, w, w8);
    k_p3<<<NBLK, 256, 0, stream>>>(ei, E, n, NBUK, NBLK, bhist, gcount, gstag, flags);
    k_p4<<<NBUK, 512, 0, stream>>>(gstag, gcount, off, dinv, rowidx, n, NBUK);

    const int gF = (n * 8 + 255) / 256;
    const int gL = (n + 31) / 32;

    // z0 -> zA(ws); hop1 zA->zS(d_out); hop2 zS->zA; fused hop3+lin zA -> d_out.
    // (fused kernel writes d_out; its gather input zA is workspace -> no race)
    k_z0<<<gF, 256, 0, stream>>>(xidx, (const float4*)emb, dinv, zA, n, flags);
    k_hop<<<gF, 256, 0, stream>>>(zA, zS, dinv, off, rowidx, n);
    k_hop<<<gF, 256, 0, stream>>>(zS, zA, dinv, off, rowidx, n);
    k_hop3_lin<<<gL, 256, 0, stream>>>(zA, dinv, off, rowidx, w8, b,
                                       (float*)d_out, n);
}